// Round 2
// baseline (987.187 us; speedup 1.0000x reference)
//
#include <hip/hip_runtime.h>
#include <hip/hip_fp16.h>

#define NPIX 65536
#define WIMG 256
#define HIMG 256

// K1 tiling: 16x4 output tile, 18x6 halo
#define TW 16
#define TH 4
#define TP 64
#define HLW 18
#define HLH 6
#define HPX 108
#define QSTR 68

__global__ void k_zero(float* __restrict__ p, int n) {
  int i = blockIdx.x * 256 + threadIdx.x;
  if (i < n) p[i] = 0.0f;
}

// Fused: x tile -> pointwise(64->192) -> depthwise 3x3 -> {gram atomics, v store}
__global__ __launch_bounds__(256)
void k_qkv(const float* __restrict__ x,
           const float* __restrict__ wqkv1,
           const float* __restrict__ wqkv2,
           const float* __restrict__ wdw1,
           const float* __restrict__ wdw2,
           __half* __restrict__ vbuf,
           float* __restrict__ gram,
           float* __restrict__ sqq,
           float* __restrict__ sqk)
{
  __shared__ __align__(16) __half xs[64 * HPX];
  __shared__ __align__(16) __half ys[64 * HPX];
  __shared__ __align__(16) __half qs[64 * QSTR];
  __shared__ __align__(16) __half ks[64 * QSTR];

  const int tid = threadIdx.x;
  const int tile = blockIdx.x;            // 0..1023
  const int br = blockIdx.y;
  const int b = blockIdx.z;
  const int tx0 = (tile & 15) * TW;
  const int ty0 = (tile >> 4) * TH;

  const float* wqkv = br ? wqkv2 : wqkv1;
  const float* wdw = br ? wdw2 : wdw1;
  const float* xb = x + ((size_t)b * 128 + br * 64) * NPIX;

  // stage x tile + halo (zero outside image; pointwise(0)=0 matches SAME pad)
  for (int idx = tid; idx < 64 * HPX; idx += 256) {
    int i = idx / HPX, p = idx - i * HPX;
    int r = p / HLW, cc = p - r * HLW;
    int gy = ty0 - 1 + r, gx = tx0 - 1 + cc;
    float v = 0.0f;
    if ((unsigned)gy < HIMG && (unsigned)gx < WIMG)
      v = xb[(size_t)i * NPIX + gy * WIMG + gx];
    xs[idx] = __float2half(v);
  }
  __syncthreads();

  for (int part = 0; part < 3; ++part) {
    // pointwise at all halo pixels: units = ch-major, 4 px per unit
    for (int u = tid; u < 64 * 27; u += 256) {
      int ch = u / 27, pg = u - ch * 27;
      const float* wrow = wqkv + (part * 64 + ch) * 64;
      float a0 = 0.f, a1 = 0.f, a2 = 0.f, a3 = 0.f;
      #pragma unroll 16
      for (int i = 0; i < 64; ++i) {
        float wv = wrow[i];
        const __half2* xp = (const __half2*)(xs + i * HPX + pg * 4);
        float2 f01 = __half22float2(xp[0]);
        float2 f23 = __half22float2(xp[1]);
        a0 += wv * f01.x;
        a1 += wv * f01.y;
        a2 += wv * f23.x;
        a3 += wv * f23.y;
      }
      __half2* yp = (__half2*)(ys + ch * HPX + pg * 4);
      yp[0] = __floats2half2_rn(a0, a1);
      yp[1] = __floats2half2_rn(a2, a3);
    }
    __syncthreads();

    // depthwise 3x3 on interior
    for (int idx = tid; idx < 64 * TP; idx += 256) {
      int c = idx >> 6, px = idx & 63;
      int py = px >> 4, pxc = px & 15;
      const float* wd = wdw + (part * 64 + c) * 9;
      float acc = 0.0f;
      #pragma unroll
      for (int ky = 0; ky < 3; ++ky)
        #pragma unroll
        for (int kx = 0; kx < 3; ++kx)
          acc += wd[ky * 3 + kx] *
                 __half2float(ys[c * HPX + (py + ky) * HLW + (pxc + kx)]);
      if (part == 0) qs[c * QSTR + px] = __float2half(acc);
      else if (part == 1) ks[c * QSTR + px] = __float2half(acc);
      else vbuf[((size_t)(br * 4 + b) * 64 + c) * NPIX + (ty0 + py) * WIMG + tx0 + pxc]
             = __float2half(acc);
    }
    __syncthreads();

    if (part == 1) {
      // per-tile gram partials -> global atomics
      float* gb = gram + (br * 4 + b) * 512;
      float* sq = sqq + (br * 4 + b) * 64;
      float* sk = sqk + (br * 4 + b) * 64;
      for (int u = tid; u < 640; u += 256) {
        int h = u / 80, r = u - h * 80;
        float acc = 0.0f;
        if (r < 64) {
          const __half* qp = qs + (h * 8 + (r >> 3)) * QSTR;
          const __half* kp = ks + (h * 8 + (r & 7)) * QSTR;
          #pragma unroll 8
          for (int p = 0; p < TP; p += 2) {
            __half2 qv = *(const __half2*)(qp + p);
            __half2 kv = *(const __half2*)(kp + p);
            acc += __low2float(qv) * __low2float(kv) +
                   __high2float(qv) * __high2float(kv);
          }
          atomicAdd(&gb[h * 64 + r], acc);
        } else if (r < 72) {
          const __half* qp = qs + (h * 8 + (r - 64)) * QSTR;
          #pragma unroll 8
          for (int p = 0; p < TP; p += 2) {
            __half2 qv = *(const __half2*)(qp + p);
            acc += __low2float(qv) * __low2float(qv) +
                   __high2float(qv) * __high2float(qv);
          }
          atomicAdd(&sq[h * 8 + (r - 64)], acc);
        } else {
          const __half* kp = ks + (h * 8 + (r - 72)) * QSTR;
          #pragma unroll 8
          for (int p = 0; p < TP; p += 2) {
            __half2 kv = *(const __half2*)(kp + p);
            acc += __low2float(kv) * __low2float(kv) +
                   __high2float(kv) * __high2float(kv);
          }
          atomicAdd(&sk[h * 8 + (r - 72)], acc);
        }
      }
    }
  }
}

// softmax(G scaled) -> attn, then Weff = w_po @ blockdiag(attn), stored TRANSPOSED [c'][o]
__global__ __launch_bounds__(64)
void k_attn(const float* __restrict__ gram, const float* __restrict__ sqq,
            const float* __restrict__ sqk,
            const float* __restrict__ wpo1,
            const float* __restrict__ wpo2,
            const float* __restrict__ t1,
            const float* __restrict__ t2,
            float* __restrict__ weff)
{
  const int br = blockIdx.x, b = blockIdx.y;
  const int t = threadIdx.x;
  __shared__ float attn[8][8][8];
  const float* gb = gram + (br * 4 + b) * 512;
  const float* sq = sqq + (br * 4 + b) * 64;
  const float* sk = sqk + (br * 4 + b) * 64;
  const float* tt = br ? t2 : t1;
  {
    int h = t >> 3, cq = t & 7;
    float ts = tt[h];
    float qn = fmaxf(sqrtf(sq[h * 8 + cq]), 1e-12f);
    float lg[8], m = -1e30f;
    #pragma unroll
    for (int d2 = 0; d2 < 8; ++d2) {
      float kn = fmaxf(sqrtf(sk[h * 8 + d2]), 1e-12f);
      lg[d2] = ts * gb[h * 64 + cq * 8 + d2] / (qn * kn);
      m = fmaxf(m, lg[d2]);
    }
    float s = 0.f;
    #pragma unroll
    for (int d2 = 0; d2 < 8; ++d2) { lg[d2] = expf(lg[d2] - m); s += lg[d2]; }
    float inv = 1.0f / s;
    #pragma unroll
    for (int d2 = 0; d2 < 8; ++d2) attn[h][cq][d2] = lg[d2] * inv;
  }
  __syncthreads();
  const float* wpo = br ? wpo2 : wpo1;
  float* wb = weff + (br * 4 + b) * 4096;
  for (int cp = 0; cp < 64; ++cp) {
    int hp = cp >> 3, ip = cp & 7;
    float acc = 0.f;
    #pragma unroll
    for (int j = 0; j < 8; ++j)
      acc += wpo[t * 64 + hp * 8 + j] * attn[hp][j][ip];
    wb[cp * 64 + t] = acc;   // transposed store: [c'][o]
  }
}

// out[b, obr*64+o, n] = sum_c Weff[obr][b][c][o] * v[1-obr][b][c][n]
__global__ __launch_bounds__(256)
void k_out(const __half* __restrict__ vbuf, const float* __restrict__ weff,
           float* __restrict__ out)
{
  __shared__ float W[4096];   // [c][o]
  const int obr = blockIdx.y, b = blockIdx.z;
  for (int i = threadIdx.x; i < 4096; i += 256)
    W[i] = weff[(obr * 4 + b) * 4096 + i];
  __syncthreads();
  const int px = blockIdx.x * 256 + threadIdx.x;
  const __half* vp = vbuf + ((size_t)((1 - obr) * 4 + b) * 64) * NPIX + px;
  float acc[64];
  #pragma unroll
  for (int o = 0; o < 64; ++o) acc[o] = 0.0f;
  for (int c = 0; c < 64; ++c) {
    float vc = __half2float(vp[(size_t)c * NPIX]);
    const float4* wr = (const float4*)(W + c * 64);
    #pragma unroll
    for (int o4 = 0; o4 < 16; ++o4) {
      float4 w4 = wr[o4];
      acc[o4 * 4 + 0] += w4.x * vc;
      acc[o4 * 4 + 1] += w4.y * vc;
      acc[o4 * 4 + 2] += w4.z * vc;
      acc[o4 * 4 + 3] += w4.w * vc;
    }
  }
  float* op = out + ((size_t)b * 128 + obr * 64) * NPIX + px;
  #pragma unroll
  for (int o = 0; o < 64; ++o) op[(size_t)o * NPIX] = acc[o];
}

extern "C" void kernel_launch(void* const* d_in, const int* in_sizes, int n_in,
                              void* d_out, int out_size, void* d_ws, size_t ws_size,
                              hipStream_t stream) {
  const float* x     = (const float*)d_in[0];
  const float* wqkv1 = (const float*)d_in[1];
  const float* wqkv2 = (const float*)d_in[2];
  const float* wdw1  = (const float*)d_in[3];
  const float* wdw2  = (const float*)d_in[4];
  const float* wpo1  = (const float*)d_in[5];
  const float* wpo2  = (const float*)d_in[6];
  const float* t1    = (const float*)d_in[7];
  const float* t2    = (const float*)d_in[8];

  char* ws = (char*)d_ws;
  __half* vbuf = (__half*)ws;                     // 2*4*64*65536*2 = 67,108,864 B
  float* gram = (float*)(ws + 67108864);          // [2][4][8][8][8] = 4096 f32
  float* sqq  = gram + 4096;                      // [2][4][64]
  float* sqk  = sqq + 512;                        // [2][4][64]
  float* weff = sqk + 512;                        // [2][4][64][64] = 32768 f32

  k_zero<<<dim3(20), dim3(256), 0, stream>>>(gram, 5120);
  k_qkv<<<dim3(1024, 2, 4), dim3(256), 0, stream>>>(x, wqkv1, wqkv2, wdw1, wdw2,
                                                    vbuf, gram, sqq, sqk);
  k_attn<<<dim3(2, 4), dim3(64), 0, stream>>>(gram, sqq, sqk, wpo1, wpo2, t1, t2, weff);
  k_out<<<dim3(256, 2, 4), dim3(256), 0, stream>>>(vbuf, weff, (float*)d_out);
}

// Round 3
// 423.749 us; speedup vs baseline: 2.3297x; 2.3297x over previous
//
#include <hip/hip_runtime.h>
#include <hip/hip_fp16.h>

#define NPIX 65536
#define WIMG 256
#define HIMG 256
#define TW 16
#define TH 8
#define HSTR 24      // padded halo row stride (halves)
#define HROWS 10
#define HSLOTS 240   // HROWS*HSTR
#define MT_N 15      // m-tiles of 16 over 240 slots

typedef __attribute__((ext_vector_type(8))) _Float16 half8;
typedef __attribute__((ext_vector_type(4))) float f32x4;

__device__ __forceinline__ unsigned int h2u(__half2 h) {
  union { __half2 h; unsigned int u; } c; c.h = h; return c.u;
}
__device__ __forceinline__ __half2 u2h(unsigned int u) {
  union { unsigned int u; __half2 h; } c; c.u = u; return c.h;
}
// xs layout: [px][c] with 16B-block XOR swizzle; returns half-index
__device__ __forceinline__ int xs_idx(int px, int c) {
  return px * 64 + ((((c >> 3) ^ (px & 7)) << 3) | (c & 7));
}
// qs/ks layout: [ch][px 0..127] swizzled; pxblk = px>>3; returns half-index of 8-px block
__device__ __forceinline__ int qk_idx(int ch, int pxblk) {
  return ch * 128 + ((pxblk ^ (ch & 7)) << 3);
}

__global__ void k_zero(float* __restrict__ p, int n) {
  int i = blockIdx.x * 256 + threadIdx.x;
  if (i < n) p[i] = 0.0f;
}

__global__ __launch_bounds__(256, 2)
void k_qkv(const float* __restrict__ x,
           const float* __restrict__ wqkv1, const float* __restrict__ wqkv2,
           const float* __restrict__ wdw1, const float* __restrict__ wdw2,
           __half* __restrict__ vbuf, float* __restrict__ gram,
           float* __restrict__ sqq, float* __restrict__ sqk)
{
  __shared__ __align__(16) _Float16 xs[HSLOTS * 64];   // 30720 B
  __shared__ __align__(16) _Float16 ys[64 * HSLOTS];   // 30720 B (reused as ks[64][128])
  __shared__ __align__(16) _Float16 qs[64 * 128];      // 16384 B

  const int tid = threadIdx.x;
  const int lane = tid & 63;
  const int wid = tid >> 6;
  const int tile = blockIdx.x;
  const int br = blockIdx.y;
  const int b = blockIdx.z;
  const int tx0 = (tile & 15) * TW;
  const int ty0 = (tile >> 4) * TH;

  const float* wqkv = br ? wqkv2 : wqkv1;
  const float* wdw  = br ? wdw2 : wdw1;
  const float* xb = x + ((size_t)b * 128 + br * 64) * NPIX;

  // ---- stage x halo tile, f32 -> f16, transposed [px][c] with swizzle ----
  for (int u = tid; u < 32 * HSLOTS; u += 256) {
    int cp = u / HSLOTS, px = u - cp * HSLOTS;
    int hy = px / HSTR, hx = px - hy * HSTR;
    int gy = ty0 - 1 + hy, gx = tx0 - 1 + hx;
    float a0 = 0.f, a1 = 0.f;
    if (hx < 18 && (unsigned)gy < HIMG && (unsigned)gx < WIMG) {
      const float* pp = xb + (size_t)(cp * 2) * NPIX + gy * WIMG + gx;
      a0 = pp[0]; a1 = pp[NPIX];
    }
    *(__half2*)(xs + xs_idx(px, cp * 2)) = __floats2half2_rn(a0, a1);
  }
  __syncthreads();

  // parts: p=0 -> v (w part 2), p=1 -> q (w part 0), p=2 -> k (w part 1)
  for (int p = 0; p < 3; ++p) {
    const int pw = (p == 0) ? 2 : (p - 1);
    if (p) __syncthreads();

    // ---- w B-fragments into registers (global, L2-resident) ----
    half8 wf[2][4];
    #pragma unroll
    for (int nt = 0; nt < 4; ++nt)
      #pragma unroll
      for (int kc = 0; kc < 2; ++kc) {
        const float* wr = wqkv + (size_t)(pw * 64 + nt * 16 + (lane & 15)) * 64
                                 + kc * 32 + (lane >> 4) * 8;
        float4 wa = *(const float4*)wr;
        float4 wb4 = *(const float4*)(wr + 4);
        half8 h;
        h[0] = (_Float16)wa.x;  h[1] = (_Float16)wa.y;
        h[2] = (_Float16)wa.z;  h[3] = (_Float16)wa.w;
        h[4] = (_Float16)wb4.x; h[5] = (_Float16)wb4.y;
        h[6] = (_Float16)wb4.z; h[7] = (_Float16)wb4.w;
        wf[kc][nt] = h;
      }

    // ---- pointwise via MFMA: y[o][px] = sum_c w[o][c] * x[px][c] ----
    for (int mt = wid; mt < MT_N; mt += 4) {
      int px = mt * 16 + (lane & 15);
      half8 af0 = *(const half8*)(xs + px * 64 + ((((lane >> 4)    ) ^ (px & 7)) << 3));
      half8 af1 = *(const half8*)(xs + px * 64 + (((4 + (lane >> 4)) ^ (px & 7)) << 3));
      f32x4 acc[4] = {{0,0,0,0},{0,0,0,0},{0,0,0,0},{0,0,0,0}};
      #pragma unroll
      for (int nt = 0; nt < 4; ++nt) {
        acc[nt] = __builtin_amdgcn_mfma_f32_16x16x32_f16(af0, wf[0][nt], acc[nt], 0, 0, 0);
        acc[nt] = __builtin_amdgcn_mfma_f32_16x16x32_f16(af1, wf[1][nt], acc[nt], 0, 0, 0);
      }
      int pxd = mt * 16 + (lane >> 4) * 4;
      #pragma unroll
      for (int nt = 0; nt < 4; ++nt) {
        int o = nt * 16 + (lane & 15);
        __half2* dst = (__half2*)(ys + o * HSLOTS + pxd);
        dst[0] = __floats2half2_rn(acc[nt][0], acc[nt][1]);
        dst[1] = __floats2half2_rn(acc[nt][2], acc[nt][3]);
      }
    }
    __syncthreads();

    // ---- depthwise 3x3, packed half2, 16 px per unit ----
    __half2 dacc[2][8];
    #pragma unroll
    for (int uu = 0; uu < 2; ++uu) {
      int u = tid + uu * 256;
      int o = u >> 3, row = u & 7;
      const float* wdp = wdw + (size_t)(pw * 64 + o) * 9;
      __half2 w2[9];
      #pragma unroll
      for (int j = 0; j < 9; ++j) w2[j] = __half2half2(__float2half(wdp[j]));
      __half2 a[8];
      #pragma unroll
      for (int k2 = 0; k2 < 8; ++k2) a[k2] = u2h(0u);
      #pragma unroll
      for (int ky = 0; ky < 3; ++ky) {
        const _Float16* rp = ys + o * HSLOTS + (row + ky) * HSTR;
        uint4 ra = *(const uint4*)rp;
        uint4 rb = *(const uint4*)(rp + 8);
        unsigned int rc = *(const unsigned int*)(rp + 16);
        unsigned int A[9] = {ra.x, ra.y, ra.z, ra.w, rb.x, rb.y, rb.z, rb.w, rc};
        #pragma unroll
        for (int k2 = 0; k2 < 8; ++k2) {
          unsigned int M = (A[k2] >> 16) | (A[k2 + 1] << 16);
          a[k2] = __hfma2(w2[ky * 3 + 0], u2h(A[k2]), a[k2]);
          a[k2] = __hfma2(w2[ky * 3 + 1], u2h(M), a[k2]);
          a[k2] = __hfma2(w2[ky * 3 + 2], u2h(A[k2 + 1]), a[k2]);
        }
      }
      #pragma unroll
      for (int k2 = 0; k2 < 8; ++k2) dacc[uu][k2] = a[k2];
    }

    if (p == 0) {
      // v -> global (fp16)
      #pragma unroll
      for (int uu = 0; uu < 2; ++uu) {
        int u = tid + uu * 256;
        int o = u >> 3, row = u & 7;
        __half* vrow = (__half*)(vbuf + ((size_t)((br * 4 + b) * 64 + o)) * NPIX
                                 + (ty0 + row) * WIMG + tx0);
        uint4 s0 = {h2u(dacc[uu][0]), h2u(dacc[uu][1]), h2u(dacc[uu][2]), h2u(dacc[uu][3])};
        uint4 s1 = {h2u(dacc[uu][4]), h2u(dacc[uu][5]), h2u(dacc[uu][6]), h2u(dacc[uu][7])};
        *(uint4*)vrow = s0;
        *(uint4*)(vrow + 8) = s1;
      }
    } else {
      _Float16* dst = (p == 1) ? qs : ys;   // ks reuses ys region
      float* sq = (p == 1) ? sqq : sqk;
      if (p == 2) __syncthreads();          // all ys reads done before overwrite
      #pragma unroll
      for (int uu = 0; uu < 2; ++uu) {
        int u = tid + uu * 256;
        int o = u >> 3, row = u & 7;
        uint4 s0 = {h2u(dacc[uu][0]), h2u(dacc[uu][1]), h2u(dacc[uu][2]), h2u(dacc[uu][3])};
        uint4 s1 = {h2u(dacc[uu][4]), h2u(dacc[uu][5]), h2u(dacc[uu][6]), h2u(dacc[uu][7])};
        *(uint4*)(dst + qk_idx(o, 2 * row))     = s0;
        *(uint4*)(dst + qk_idx(o, 2 * row + 1)) = s1;
        float s = 0.f;
        #pragma unroll
        for (int k2 = 0; k2 < 8; ++k2) {
          float2 f = __half22float2(dacc[uu][k2]);
          s += f.x * f.x + f.y * f.y;
        }
        s += __shfl_xor(s, 1); s += __shfl_xor(s, 2); s += __shfl_xor(s, 4);
        if ((tid & 7) == 0) atomicAdd(&sq[(br * 4 + b) * 64 + o], s);
      }
      if (p == 2) {
        __syncthreads();
        // ---- gram: diag head-tiles via MFMA, K=128 px ----
        const _Float16* ksb = ys;
        f32x4 g = {0, 0, 0, 0};
        int ch = wid * 16 + (lane & 15);
        #pragma unroll
        for (int kc = 0; kc < 4; ++kc) {
          int pb = kc * 4 + (lane >> 4);
          half8 aq = *(const half8*)(qs  + qk_idx(ch, pb));
          half8 bk = *(const half8*)(ksb + qk_idx(ch, pb));
          g = __builtin_amdgcn_mfma_f32_16x16x32_f16(aq, bk, g, 0, 0, 0);
        }
        if (((lane >> 3) & 1) == (lane >> 5)) {
          float* gb = gram + (br * 4 + b) * 512;
          int kch = ch;
          int qc0 = wid * 16 + (lane >> 4) * 4;
          #pragma unroll
          for (int r = 0; r < 4; ++r) {
            int qch = qc0 + r;
            atomicAdd(&gb[(qch >> 3) * 64 + (qch & 7) * 8 + (kch & 7)], g[r]);
          }
        }
      }
    }
  }
}

// softmax(G scaled) -> attn, Weff = w_po @ blockdiag(attn), stored transposed [c'][o]
__global__ __launch_bounds__(64)
void k_attn(const float* __restrict__ gram, const float* __restrict__ sqq,
            const float* __restrict__ sqk,
            const float* __restrict__ wpo1, const float* __restrict__ wpo2,
            const float* __restrict__ t1, const float* __restrict__ t2,
            float* __restrict__ weff)
{
  const int br = blockIdx.x, b = blockIdx.y;
  const int t = threadIdx.x;
  __shared__ float attn[8][8][8];
  const float* gb = gram + (br * 4 + b) * 512;
  const float* sq = sqq + (br * 4 + b) * 64;
  const float* sk = sqk + (br * 4 + b) * 64;
  const float* tt = br ? t2 : t1;
  {
    int h = t >> 3, cq = t & 7;
    float ts = tt[h];
    float qn = fmaxf(sqrtf(sq[h * 8 + cq]), 1e-12f);
    float lg[8], m = -1e30f;
    #pragma unroll
    for (int d2 = 0; d2 < 8; ++d2) {
      float kn = fmaxf(sqrtf(sk[h * 8 + d2]), 1e-12f);
      lg[d2] = ts * gb[h * 64 + cq * 8 + d2] / (qn * kn);
      m = fmaxf(m, lg[d2]);
    }
    float s = 0.f;
    #pragma unroll
    for (int d2 = 0; d2 < 8; ++d2) { lg[d2] = expf(lg[d2] - m); s += lg[d2]; }
    float inv = 1.0f / s;
    #pragma unroll
    for (int d2 = 0; d2 < 8; ++d2) attn[h][cq][d2] = lg[d2] * inv;
  }
  __syncthreads();
  const float* wpo = br ? wpo2 : wpo1;
  float* wb = weff + (br * 4 + b) * 4096;
  for (int cp = 0; cp < 64; ++cp) {
    int hp = cp >> 3, ip = cp & 7;
    float acc = 0.f;
    #pragma unroll
    for (int j = 0; j < 8; ++j)
      acc += wpo[t * 64 + hp * 8 + j] * attn[hp][j][ip];
    wb[cp * 64 + t] = acc;   // [c'][o]
  }
}

// out[b, obr*64+o, px] = sum_c Weff[obr][b][c][o] * v[1-obr][b][c][px]
// W read via uniform address -> SGPR broadcast (no LDS)
__global__ __launch_bounds__(256)
void k_out(const __half* __restrict__ vbuf, const float* __restrict__ weff,
           float* __restrict__ out)
{
  const int obr = blockIdx.y, b = blockIdx.z;
  const int px = blockIdx.x * 256 + threadIdx.x;
  const float* wb = weff + (obr * 4 + b) * 4096;   // [c][o]
  const __half* vp = vbuf + ((size_t)((1 - obr) * 4 + b) * 64) * NPIX + px;
  float acc[64];
  #pragma unroll
  for (int o = 0; o < 64; ++o) acc[o] = 0.0f;
  for (int c = 0; c < 64; ++c) {
    float vc = __half2float(vp[(size_t)c * NPIX]);
    const float* wr = wb + c * 64;   // block-uniform -> s_load
    #pragma unroll
    for (int o = 0; o < 64; ++o) acc[o] = fmaf(wr[o], vc, acc[o]);
  }
  float* op = out + ((size_t)b * 128 + obr * 64) * NPIX + px;
  #pragma unroll
  for (int o = 0; o < 64; ++o) op[(size_t)o * NPIX] = acc[o];
}

extern "C" void kernel_launch(void* const* d_in, const int* in_sizes, int n_in,
                              void* d_out, int out_size, void* d_ws, size_t ws_size,
                              hipStream_t stream) {
  const float* x     = (const float*)d_in[0];
  const float* wqkv1 = (const float*)d_in[1];
  const float* wqkv2 = (const float*)d_in[2];
  const float* wdw1  = (const float*)d_in[3];
  const float* wdw2  = (const float*)d_in[4];
  const float* wpo1  = (const float*)d_in[5];
  const float* wpo2  = (const float*)d_in[6];
  const float* t1    = (const float*)d_in[7];
  const float* t2    = (const float*)d_in[8];

  char* ws = (char*)d_ws;
  __half* vbuf = (__half*)ws;                     // 67,108,864 B
  float* gram = (float*)(ws + 67108864);          // [2][4][8][8][8]
  float* sqq  = gram + 4096;
  float* sqk  = sqq + 512;
  float* weff = sqk + 512;                        // [2][4][64][64]

  k_zero<<<dim3(20), dim3(256), 0, stream>>>(gram, 5120);
  k_qkv<<<dim3(512, 2, 4), dim3(256), 0, stream>>>(x, wqkv1, wqkv2, wdw1, wdw2,
                                                   vbuf, gram, sqq, sqk);
  k_attn<<<dim3(2, 4), dim3(64), 0, stream>>>(gram, sqq, sqk, wpo1, wpo2, t1, t2, weff);
  k_out<<<dim3(256, 2, 4), dim3(256), 0, stream>>>(vbuf, weff, (float*)d_out);
}